// Round 8
// baseline (452.725 us; speedup 1.0000x reference)
//
#include <hip/hip_runtime.h>

#define DF 128
#define RB 512            // nodes per bucket (power of two)
#define RB_SHIFT 9
#define NB_MAX 256        // supports n <= 131072
#define CHUNK 8192        // edges per binning block

// ---------------- CSR build (bucketed, coalesced) ----------------

__global__ void k_bhist(const int* __restrict__ dst, int* __restrict__ bcnt, int e){
  __shared__ int h[NB_MAX];
  int t = threadIdx.x;
  h[t] = 0;
  __syncthreads();
  int base = blockIdx.x*CHUNK;
  for(int k=0;k<CHUNK/256;k++){
    int i = base + t + k*256;
    if(i<e) atomicAdd(&h[dst[i]>>RB_SHIFT], 1);
  }
  __syncthreads();
  if(h[t]) atomicAdd(&bcnt[t], h[t]);
}

__global__ void k_bscan(const int* __restrict__ bcnt, int* __restrict__ bbase,
                        int* __restrict__ bcur, int e){
  __shared__ int sh[NB_MAX];
  int t = threadIdx.x;
  int c = bcnt[t];
  sh[t] = c;
  __syncthreads();
  for(int off=1; off<256; off<<=1){
    int v = (t>=off)? sh[t-off]:0;
    __syncthreads();
    sh[t]+=v;
    __syncthreads();
  }
  int excl = sh[t]-c;
  bbase[t]=excl; bcur[t]=excl;
  if(t==255) bbase[256]=sh[255];   // == e
}

__launch_bounds__(256)
__global__ void k_binscatter(const int* __restrict__ src, const int* __restrict__ dst,
                             int* __restrict__ bcur, int2* __restrict__ binned, int e){
  __shared__ int h[NB_MAX];
  __shared__ int lexcl[NB_MAX];
  __shared__ int lcur[NB_MAX];
  __shared__ int gbase[NB_MAX];
  __shared__ int2 pairs[CHUNK];
  int t = threadIdx.x;
  int c0 = blockIdx.x*CHUNK;
  int cc = min(CHUNK, e - c0);
  h[t]=0;
  __syncthreads();
  for(int k=0;k<CHUNK/256;k++){
    int i = t + k*256;
    if(i<cc) atomicAdd(&h[dst[c0+i]>>RB_SHIFT], 1);
  }
  __syncthreads();
  int hc = h[t];
  lexcl[t]=hc;
  __syncthreads();
  for(int off=1; off<256; off<<=1){
    int v = (t>=off)? lexcl[t-off]:0;
    __syncthreads();
    lexcl[t]+=v;
    __syncthreads();
  }
  int incl = lexcl[t];
  lexcl[t] = incl - hc;
  lcur[t]  = incl - hc;
  gbase[t] = hc ? atomicAdd(&bcur[t], hc) : 0;
  __syncthreads();
  for(int k=0;k<CHUNK/256;k++){
    int i = t + k*256;
    if(i<cc){
      int d = dst[c0+i], s = src[c0+i];
      int lp = atomicAdd(&lcur[d>>RB_SHIFT], 1);
      pairs[lp] = make_int2(d, s);
    }
  }
  __syncthreads();
  for(int k=0;k<CHUNK/256;k++){
    int p = t + k*256;
    if(p<cc){
      int2 pr = pairs[p];
      int b = pr.x>>RB_SHIFT;
      binned[gbase[b] + (p - lexcl[b])] = pr;
    }
  }
}

__launch_bounds__(256)
__global__ void k_localcsr(const int2* __restrict__ binned, const int* __restrict__ bbase,
                           int* __restrict__ rp, int* __restrict__ csr,
                           float* __restrict__ dinv, int n, int e){
  __shared__ int cnt[RB];
  __shared__ int sh[256];
  __shared__ int cur[RB];
  int b = blockIdx.x, t = threadIdx.x;
  int node0 = b<<RB_SHIFT;
  int e0 = bbase[b], e1 = bbase[b+1];
  cnt[t]=0; cnt[t+256]=0;
  __syncthreads();
  for(int i=e0+t; i<e1; i+=256)
    atomicAdd(&cnt[binned[i].x - node0], 1);
  __syncthreads();
  int c0 = cnt[2*t], c1 = cnt[2*t+1];
  int s = c0+c1;
  sh[t]=s;
  __syncthreads();
  for(int off=1; off<256; off<<=1){
    int v = (t>=off)? sh[t-off]:0;
    __syncthreads();
    sh[t]+=v;
    __syncthreads();
  }
  int excl = sh[t]-s;
  int g0 = node0+2*t, g1 = node0+2*t+1;
  if(g0<n){ rp[g0]=e0+excl;    dinv[g0]=rsqrtf((float)(c0+1)); }
  if(g1<n){ rp[g1]=e0+excl+c0; dinv[g1]=rsqrtf((float)(c1+1)); }
  cur[2*t]=excl; cur[2*t+1]=excl+c0;
  if(b==0 && t==0) rp[n]=e;
  __syncthreads();
  for(int i=e0+t; i<e1; i+=256){
    int2 pr = binned[i];
    int lp = atomicAdd(&cur[pr.x - node0], 1);
    csr[e0+lp] = pr.y;
  }
}

// ---------------- prescale: g0 = dinv .* x ----------------

__global__ void k_prescale(const float* __restrict__ x, const float* __restrict__ dinv,
                           float* __restrict__ g, int n){
  int i = blockIdx.x*256 + threadIdx.x;     // float4 index
  if(i < n*(DF/4)){
    float4 v = ((const float4*)x)[i];
    float dv = dinv[i>>5];
    v.x*=dv; v.y*=dv; v.z*=dv; v.w*=dv;
    ((float4*)g)[i] = v;
  }
}

// ---------------- Fused layer: gather(g) -> z=dv*s -> y=zW+b -> act ----------------
// g rows are pre-scaled (dinv_j * h_j). 32 nodes/block, 256 threads.
// Each 32-lane group owns 4 nodes end-to-end: gather into its private LDS rows,
// wave-local waitcnt (NO block barrier), then GEMM. Two groups per wave64 run in
// lockstep; groups in different waves flow independently -> memory stays fed.

__launch_bounds__(256, 8)
__global__ void k_fused(const float* __restrict__ g, const int* __restrict__ rp,
                        const int* __restrict__ cs, const float* __restrict__ dinv,
                        const float* __restrict__ W, const float* __restrict__ bias,
                        float* __restrict__ out, int n, int scale_out){
  __shared__ float zs[32][132];
  int t = threadIdx.x;
  int grp = t>>5, lane = t&31;
  int node0 = blockIdx.x*32;
  int c4 = lane*4;
  // ---- phase 1: gather (group-private rows zs[grp*4 .. grp*4+3]) ----
  for(int nn=0; nn<4; nn++){
    int node = node0 + grp*4 + nn;
    if(node<n){
      float4 acc = *(const float4*)(g + (size_t)node*DF + c4);   // self (pre-scaled)
      float4 acc2 = make_float4(0.f,0.f,0.f,0.f);
      int e0=rp[node], e1=rp[node+1];
      int e=e0;
      for(; e+1<e1; e+=2){
        int s0=cs[e], s1=cs[e+1];
        float4 v0 = *(const float4*)(g + (size_t)s0*DF + c4);
        float4 v1 = *(const float4*)(g + (size_t)s1*DF + c4);
        acc.x+=v0.x;  acc.y+=v0.y;  acc.z+=v0.z;  acc.w+=v0.w;
        acc2.x+=v1.x; acc2.y+=v1.y; acc2.z+=v1.z; acc2.w+=v1.w;
      }
      if(e<e1){
        int s0=cs[e];
        float4 v0=*(const float4*)(g + (size_t)s0*DF + c4);
        acc.x+=v0.x; acc.y+=v0.y; acc.z+=v0.z; acc.w+=v0.w;
      }
      float dv = dinv[node];
      acc.x = dv*(acc.x+acc2.x);
      acc.y = dv*(acc.y+acc2.y);
      acc.z = dv*(acc.z+acc2.z);
      acc.w = dv*(acc.w+acc2.w);
      *(float4*)&zs[grp*4+nn][c4] = acc;
    }
  }
  // wave-local LDS sync: rows are written and read by the same wave.
  // Drain LDS writes, then fence compiler reordering (rule: sched_barrier after waitcnt).
  asm volatile("s_waitcnt lgkmcnt(0)" ::: "memory");
  __builtin_amdgcn_wave_barrier();
  __builtin_amdgcn_sched_barrier(0);
  // ---- phase 2: y = z @ W + b ----
  const float4* Wr = (const float4*)W;      // [128][32] float4 view
  int r0 = grp*4;
  float4 a0 = make_float4(0.f,0.f,0.f,0.f);
  float4 a1 = a0, a2 = a0, a3 = a0;
  for(int k=0;k<128;k+=4){
    float4 s0 = *(const float4*)&zs[r0  ][k];
    float4 s1 = *(const float4*)&zs[r0+1][k];
    float4 s2 = *(const float4*)&zs[r0+2][k];
    float4 s3 = *(const float4*)&zs[r0+3][k];
#define STEP(KK, C) { float4 w = Wr[(k+KK)*32 + lane];                     \
    a0.x = fmaf(s0.C, w.x, a0.x); a0.y = fmaf(s0.C, w.y, a0.y);            \
    a0.z = fmaf(s0.C, w.z, a0.z); a0.w = fmaf(s0.C, w.w, a0.w);            \
    a1.x = fmaf(s1.C, w.x, a1.x); a1.y = fmaf(s1.C, w.y, a1.y);            \
    a1.z = fmaf(s1.C, w.z, a1.z); a1.w = fmaf(s1.C, w.w, a1.w);            \
    a2.x = fmaf(s2.C, w.x, a2.x); a2.y = fmaf(s2.C, w.y, a2.y);            \
    a2.z = fmaf(s2.C, w.z, a2.z); a2.w = fmaf(s2.C, w.w, a2.w);            \
    a3.x = fmaf(s3.C, w.x, a3.x); a3.y = fmaf(s3.C, w.y, a3.y);            \
    a3.z = fmaf(s3.C, w.z, a3.z); a3.w = fmaf(s3.C, w.w, a3.w); }
    STEP(0, x) STEP(1, y) STEP(2, z) STEP(3, w)
#undef STEP
  }
  float4 bz = ((const float4*)bias)[lane];
  float4 av[4] = {a0, a1, a2, a3};
  for(int nn=0; nn<4; nn++){
    int node = node0 + r0 + nn;
    if(node<n){
      float4 y = av[nn];
      y.x += bz.x; y.y += bz.y; y.z += bz.z; y.w += bz.w;
      y.x = fmaxf(y.x, 0.f); y.y = fmaxf(y.y, 0.f);
      y.z = fmaxf(y.z, 0.f); y.w = fmaxf(y.w, 0.f);
      if(scale_out){
        float dv = dinv[node];
        y.x*=dv; y.y*=dv; y.z*=dv; y.w*=dv;
      }
      *(float4*)(out + (size_t)node*DF + c4) = y;
    }
  }
}

// ---------------- Final layer: 128 -> 5 ----------------

__launch_bounds__(256)
__global__ void k_gemm5(const float* __restrict__ X, const float* __restrict__ W2,
                        const float* __restrict__ dinv, float* __restrict__ out, int n){
  __shared__ float xs[32][129];
  __shared__ float wsh[640];
  int t=threadIdx.x;
  int row0=blockIdx.x*32;
  for(int idx=t; idx<640; idx+=256) wsh[idx]=W2[idx];
  for(int idx=t; idx<1024; idx+=256){
    int r=idx>>5, k4=(idx&31)*4;
    int gr=row0+r;
    float4 v = (gr<n)? *(const float4*)(X+(size_t)gr*DF+k4) : make_float4(0.f,0.f,0.f,0.f);
    xs[r][k4]=v.x; xs[r][k4+1]=v.y; xs[r][k4+2]=v.z; xs[r][k4+3]=v.w;
  }
  __syncthreads();
  int r=t>>3, c=t&7;
  int gr=row0+r;
  if(c<5 && gr<n){
    float acc=0.f;
    #pragma unroll
    for(int k=0;k<128;k++) acc = fmaf(xs[r][k], wsh[k*5+c], acc);
    out[(size_t)gr*5+c] = dinv[gr]*acc;
  }
}

__global__ void k_agg5(const float* __restrict__ ht, const int* __restrict__ rp,
                       const int* __restrict__ cs, const float* __restrict__ dinv,
                       const float* __restrict__ b2, float* __restrict__ out, int n){
  int idx = blockIdx.x*256+threadIdx.x;
  int node = idx>>3, c = idx&7;
  if(node>=n || c>=5) return;
  float acc = ht[(size_t)node*5+c];
  int e0=rp[node], e1=rp[node+1];
  for(int e=e0;e<e1;e++){
    acc += ht[(size_t)cs[e]*5+c];
  }
  out[(size_t)node*5+c] = fmaf(dinv[node], acc, b2[c]);
}

// ---------------- launch ----------------

extern "C" void kernel_launch(void* const* d_in, const int* in_sizes, int n_in,
                              void* d_out, int out_size, void* d_ws, size_t ws_size,
                              hipStream_t stream){
  const float* x  = (const float*)d_in[0];
  const int*   ei = (const int*)  d_in[1];
  const float* W0 = (const float*)d_in[2];
  const float* b0 = (const float*)d_in[3];
  const float* W1 = (const float*)d_in[4];
  const float* b1 = (const float*)d_in[5];
  const float* W2 = (const float*)d_in[6];
  const float* b2 = (const float*)d_in[7];
  int n = in_sizes[0]/DF;
  int e = in_sizes[1]/2;
  const int* srcp = ei;
  const int* dstp = ei + e;

  char* ws = (char*)d_ws;
  size_t off=0;
  auto take=[&](size_t bytes)->char*{
    char* p = ws+off;
    off = (off+bytes+511)&~(size_t)511;
    return p;
  };
  int*   bcnt = (int*)  take((size_t)NB_MAX*4);
  int*   bbase= (int*)  take((size_t)(NB_MAX+1)*4);
  int*   bcur = (int*)  take((size_t)NB_MAX*4);
  int*   rp   = (int*)  take((size_t)(n+1)*4);
  int*   csr  = (int*)  take((size_t)e*4);
  float* dinv = (float*)take((size_t)n*4);
  float* bufA = (float*)take((size_t)n*DF*4);
  float* bufB = (float*)take((size_t)n*DF*4);
  int2*  binned = (int2*)bufB;   // dead before first write of bufB

  hipMemsetAsync(bcnt, 0, (size_t)NB_MAX*4, stream);

  int nb   = (n + RB-1) >> RB_SHIFT;
  int ncb  = (e + CHUNK-1) / CHUNK;
  k_bhist     <<<ncb, 256, 0, stream>>>(dstp, bcnt, e);
  k_bscan     <<<1,   256, 0, stream>>>(bcnt, bbase, bcur, e);
  k_binscatter<<<ncb, 256, 0, stream>>>(srcp, dstp, bcur, binned, e);
  k_localcsr  <<<nb,  256, 0, stream>>>(binned, bbase, rp, csr, dinv, n, e);

  int nfb = (n+31)/32;
  k_prescale<<<(n*(DF/4)+255)/256, 256, 0, stream>>>(x, dinv, bufA, n);
  // layer 1: gather g0(bufA) -> bufB = dinv*relu(y)
  k_fused   <<<nfb, 256, 0, stream>>>(bufA, rp, csr, dinv, W0, b0, bufB, n, 1);
  // layer 2: gather g1(bufB) -> bufA = relu(y)  (plain h2)
  k_fused   <<<nfb, 256, 0, stream>>>(bufB, rp, csr, dinv, W1, b1, bufA, n, 0);
  // layer 3: ht = dinv*(h2 @ W2) in bufB, then aggregate
  k_gemm5   <<<(n+31)/32, 256, 0, stream>>>(bufA, W2, dinv, (float*)bufB, n);
  k_agg5    <<<((n*8)+255)/256, 256, 0, stream>>>((float*)bufB, rp, csr, dinv, b2, (float*)d_out, n);
}

// Round 9
// 452.366 us; speedup vs baseline: 1.0008x; 1.0008x over previous
//
#include <hip/hip_runtime.h>

#define DF 128
#define RB 512            // nodes per bucket (power of two)
#define RB_SHIFT 9
#define NB_MAX 256        // supports n <= 131072
#define CHUNK 8192        // edges per binning block

// ---------------- CSR build (bucketed, coalesced) ----------------

__global__ void k_bhist(const int* __restrict__ dst, int* __restrict__ bcnt, int e){
  __shared__ int h[NB_MAX];
  int t = threadIdx.x;
  h[t] = 0;
  __syncthreads();
  int base = blockIdx.x*CHUNK;
  for(int k=0;k<CHUNK/256;k++){
    int i = base + t + k*256;
    if(i<e) atomicAdd(&h[dst[i]>>RB_SHIFT], 1);
  }
  __syncthreads();
  if(h[t]) atomicAdd(&bcnt[t], h[t]);
}

__global__ void k_bscan(const int* __restrict__ bcnt, int* __restrict__ bbase,
                        int* __restrict__ bcur, int e){
  __shared__ int sh[NB_MAX];
  int t = threadIdx.x;
  int c = bcnt[t];
  sh[t] = c;
  __syncthreads();
  for(int off=1; off<256; off<<=1){
    int v = (t>=off)? sh[t-off]:0;
    __syncthreads();
    sh[t]+=v;
    __syncthreads();
  }
  int excl = sh[t]-c;
  bbase[t]=excl; bcur[t]=excl;
  if(t==255) bbase[256]=sh[255];   // == e
}

__launch_bounds__(256)
__global__ void k_binscatter(const int* __restrict__ src, const int* __restrict__ dst,
                             int* __restrict__ bcur, int2* __restrict__ binned, int e){
  __shared__ int h[NB_MAX];
  __shared__ int lexcl[NB_MAX];
  __shared__ int lcur[NB_MAX];
  __shared__ int gbase[NB_MAX];
  __shared__ int2 pairs[CHUNK];
  int t = threadIdx.x;
  int c0 = blockIdx.x*CHUNK;
  int cc = min(CHUNK, e - c0);
  h[t]=0;
  __syncthreads();
  for(int k=0;k<CHUNK/256;k++){
    int i = t + k*256;
    if(i<cc) atomicAdd(&h[dst[c0+i]>>RB_SHIFT], 1);
  }
  __syncthreads();
  int hc = h[t];
  lexcl[t]=hc;
  __syncthreads();
  for(int off=1; off<256; off<<=1){
    int v = (t>=off)? lexcl[t-off]:0;
    __syncthreads();
    lexcl[t]+=v;
    __syncthreads();
  }
  int incl = lexcl[t];
  lexcl[t] = incl - hc;
  lcur[t]  = incl - hc;
  gbase[t] = hc ? atomicAdd(&bcur[t], hc) : 0;
  __syncthreads();
  for(int k=0;k<CHUNK/256;k++){
    int i = t + k*256;
    if(i<cc){
      int d = dst[c0+i], s = src[c0+i];
      int lp = atomicAdd(&lcur[d>>RB_SHIFT], 1);
      pairs[lp] = make_int2(d, s);
    }
  }
  __syncthreads();
  for(int k=0;k<CHUNK/256;k++){
    int p = t + k*256;
    if(p<cc){
      int2 pr = pairs[p];
      int b = pr.x>>RB_SHIFT;
      binned[gbase[b] + (p - lexcl[b])] = pr;
    }
  }
}

__launch_bounds__(256)
__global__ void k_localcsr(const int2* __restrict__ binned, const int* __restrict__ bbase,
                           int* __restrict__ rp, int* __restrict__ csr,
                           float* __restrict__ dinv, int n, int e){
  __shared__ int cnt[RB];
  __shared__ int sh[256];
  __shared__ int cur[RB];
  int b = blockIdx.x, t = threadIdx.x;
  int node0 = b<<RB_SHIFT;
  int e0 = bbase[b], e1 = bbase[b+1];
  cnt[t]=0; cnt[t+256]=0;
  __syncthreads();
  for(int i=e0+t; i<e1; i+=256)
    atomicAdd(&cnt[binned[i].x - node0], 1);
  __syncthreads();
  int c0 = cnt[2*t], c1 = cnt[2*t+1];
  int s = c0+c1;
  sh[t]=s;
  __syncthreads();
  for(int off=1; off<256; off<<=1){
    int v = (t>=off)? sh[t-off]:0;
    __syncthreads();
    sh[t]+=v;
    __syncthreads();
  }
  int excl = sh[t]-s;
  int g0 = node0+2*t, g1 = node0+2*t+1;
  if(g0<n){ rp[g0]=e0+excl;    dinv[g0]=rsqrtf((float)(c0+1)); }
  if(g1<n){ rp[g1]=e0+excl+c0; dinv[g1]=rsqrtf((float)(c1+1)); }
  cur[2*t]=excl; cur[2*t+1]=excl+c0;
  if(b==0 && t==0) rp[n]=e;
  __syncthreads();
  for(int i=e0+t; i<e1; i+=256){
    int2 pr = binned[i];
    int lp = atomicAdd(&cur[pr.x - node0], 1);
    csr[e0+lp] = pr.y;
  }
}

// ---------------- prescale: g0 = dinv .* x ----------------

__global__ void k_prescale(const float* __restrict__ x, const float* __restrict__ dinv,
                           float* __restrict__ g, int n){
  int i = blockIdx.x*256 + threadIdx.x;     // float4 index
  if(i < n*(DF/4)){
    float4 v = ((const float4*)x)[i];
    float dv = dinv[i>>5];
    v.x*=dv; v.y*=dv; v.z*=dv; v.w*=dv;
    ((float4*)g)[i] = v;
  }
}

// ---------------- Fused layer: gather(g) -> z=dv*s -> y=zW+b -> act ----------------
// g rows are pre-scaled (dinv_j * h_j). 32 nodes/block, 256 threads.
// 4-deep gather unroll: 4 independent accumulators keep 4 rows in flight per
// group, compensating for the GEMM-phase duty cycle (waves in phase 2 issue no
// gather loads; waves in phase 1 must hold 2x the outstanding bytes).

__launch_bounds__(256, 8)
__global__ void k_fused(const float* __restrict__ g, const int* __restrict__ rp,
                        const int* __restrict__ cs, const float* __restrict__ dinv,
                        const float* __restrict__ W, const float* __restrict__ bias,
                        float* __restrict__ out, int n, int scale_out){
  __shared__ float zs[32][132];
  int t = threadIdx.x;
  int grp = t>>5, lane = t&31;
  int node0 = blockIdx.x*32;
  int c4 = lane*4;
  // ---- phase 1: gather (group-private rows zs[grp*4 .. grp*4+3]) ----
  for(int nn=0; nn<4; nn++){
    int node = node0 + grp*4 + nn;
    if(node<n){
      float4 A0 = *(const float4*)(g + (size_t)node*DF + c4);   // self (pre-scaled)
      float4 A1 = make_float4(0.f,0.f,0.f,0.f);
      float4 A2 = A1, A3 = A1;
      int e0=rp[node], e1=rp[node+1];
      int e=e0;
      for(; e+3<e1; e+=4){
        int s0=cs[e], s1=cs[e+1], s2=cs[e+2], s3=cs[e+3];
        float4 v0 = *(const float4*)(g + (size_t)s0*DF + c4);
        float4 v1 = *(const float4*)(g + (size_t)s1*DF + c4);
        float4 v2 = *(const float4*)(g + (size_t)s2*DF + c4);
        float4 v3 = *(const float4*)(g + (size_t)s3*DF + c4);
        A0.x+=v0.x; A0.y+=v0.y; A0.z+=v0.z; A0.w+=v0.w;
        A1.x+=v1.x; A1.y+=v1.y; A1.z+=v1.z; A1.w+=v1.w;
        A2.x+=v2.x; A2.y+=v2.y; A2.z+=v2.z; A2.w+=v2.w;
        A3.x+=v3.x; A3.y+=v3.y; A3.z+=v3.z; A3.w+=v3.w;
      }
      if(e+1<e1){
        int s0=cs[e], s1=cs[e+1];
        float4 v0 = *(const float4*)(g + (size_t)s0*DF + c4);
        float4 v1 = *(const float4*)(g + (size_t)s1*DF + c4);
        A0.x+=v0.x; A0.y+=v0.y; A0.z+=v0.z; A0.w+=v0.w;
        A1.x+=v1.x; A1.y+=v1.y; A1.z+=v1.z; A1.w+=v1.w;
        e+=2;
      }
      if(e<e1){
        int s0=cs[e];
        float4 v0=*(const float4*)(g + (size_t)s0*DF + c4);
        A0.x+=v0.x; A0.y+=v0.y; A0.z+=v0.z; A0.w+=v0.w;
      }
      float dv = dinv[node];
      float4 zv;
      zv.x = dv*((A0.x+A1.x)+(A2.x+A3.x));
      zv.y = dv*((A0.y+A1.y)+(A2.y+A3.y));
      zv.z = dv*((A0.z+A1.z)+(A2.z+A3.z));
      zv.w = dv*((A0.w+A1.w)+(A2.w+A3.w));
      *(float4*)&zs[grp*4+nn][c4] = zv;
    }
  }
  // wave-local LDS sync: rows are written and read by the same wave.
  asm volatile("s_waitcnt lgkmcnt(0)" ::: "memory");
  __builtin_amdgcn_wave_barrier();
  __builtin_amdgcn_sched_barrier(0);
  // ---- phase 2: y = z @ W + b ----
  const float4* Wr = (const float4*)W;      // [128][32] float4 view
  int r0 = grp*4;
  float4 a0 = make_float4(0.f,0.f,0.f,0.f);
  float4 a1 = a0, a2 = a0, a3 = a0;
  for(int k=0;k<128;k+=4){
    float4 s0 = *(const float4*)&zs[r0  ][k];
    float4 s1 = *(const float4*)&zs[r0+1][k];
    float4 s2 = *(const float4*)&zs[r0+2][k];
    float4 s3 = *(const float4*)&zs[r0+3][k];
#define STEP(KK, C) { float4 w = Wr[(k+KK)*32 + lane];                     \
    a0.x = fmaf(s0.C, w.x, a0.x); a0.y = fmaf(s0.C, w.y, a0.y);            \
    a0.z = fmaf(s0.C, w.z, a0.z); a0.w = fmaf(s0.C, w.w, a0.w);            \
    a1.x = fmaf(s1.C, w.x, a1.x); a1.y = fmaf(s1.C, w.y, a1.y);            \
    a1.z = fmaf(s1.C, w.z, a1.z); a1.w = fmaf(s1.C, w.w, a1.w);            \
    a2.x = fmaf(s2.C, w.x, a2.x); a2.y = fmaf(s2.C, w.y, a2.y);            \
    a2.z = fmaf(s2.C, w.z, a2.z); a2.w = fmaf(s2.C, w.w, a2.w);            \
    a3.x = fmaf(s3.C, w.x, a3.x); a3.y = fmaf(s3.C, w.y, a3.y);            \
    a3.z = fmaf(s3.C, w.z, a3.z); a3.w = fmaf(s3.C, w.w, a3.w); }
    STEP(0, x) STEP(1, y) STEP(2, z) STEP(3, w)
#undef STEP
  }
  float4 bz = ((const float4*)bias)[lane];
  float4 av[4] = {a0, a1, a2, a3};
  for(int nn=0; nn<4; nn++){
    int node = node0 + r0 + nn;
    if(node<n){
      float4 y = av[nn];
      y.x += bz.x; y.y += bz.y; y.z += bz.z; y.w += bz.w;
      y.x = fmaxf(y.x, 0.f); y.y = fmaxf(y.y, 0.f);
      y.z = fmaxf(y.z, 0.f); y.w = fmaxf(y.w, 0.f);
      if(scale_out){
        float dv = dinv[node];
        y.x*=dv; y.y*=dv; y.z*=dv; y.w*=dv;
      }
      *(float4*)(out + (size_t)node*DF + c4) = y;
    }
  }
}

// ---------------- Final layer: 128 -> 5 ----------------

__launch_bounds__(256)
__global__ void k_gemm5(const float* __restrict__ X, const float* __restrict__ W2,
                        const float* __restrict__ dinv, float* __restrict__ out, int n){
  __shared__ float xs[32][129];
  __shared__ float wsh[640];
  int t=threadIdx.x;
  int row0=blockIdx.x*32;
  for(int idx=t; idx<640; idx+=256) wsh[idx]=W2[idx];
  for(int idx=t; idx<1024; idx+=256){
    int r=idx>>5, k4=(idx&31)*4;
    int gr=row0+r;
    float4 v = (gr<n)? *(const float4*)(X+(size_t)gr*DF+k4) : make_float4(0.f,0.f,0.f,0.f);
    xs[r][k4]=v.x; xs[r][k4+1]=v.y; xs[r][k4+2]=v.z; xs[r][k4+3]=v.w;
  }
  __syncthreads();
  int r=t>>3, c=t&7;
  int gr=row0+r;
  if(c<5 && gr<n){
    float acc=0.f;
    #pragma unroll
    for(int k=0;k<128;k++) acc = fmaf(xs[r][k], wsh[k*5+c], acc);
    out[(size_t)gr*5+c] = dinv[gr]*acc;
  }
}

__global__ void k_agg5(const float* __restrict__ ht, const int* __restrict__ rp,
                       const int* __restrict__ cs, const float* __restrict__ dinv,
                       const float* __restrict__ b2, float* __restrict__ out, int n){
  int idx = blockIdx.x*256+threadIdx.x;
  int node = idx>>3, c = idx&7;
  if(node>=n || c>=5) return;
  float acc = ht[(size_t)node*5+c];
  int e0=rp[node], e1=rp[node+1];
  for(int e=e0;e<e1;e++){
    acc += ht[(size_t)cs[e]*5+c];
  }
  out[(size_t)node*5+c] = fmaf(dinv[node], acc, b2[c]);
}

// ---------------- launch ----------------

extern "C" void kernel_launch(void* const* d_in, const int* in_sizes, int n_in,
                              void* d_out, int out_size, void* d_ws, size_t ws_size,
                              hipStream_t stream){
  const float* x  = (const float*)d_in[0];
  const int*   ei = (const int*)  d_in[1];
  const float* W0 = (const float*)d_in[2];
  const float* b0 = (const float*)d_in[3];
  const float* W1 = (const float*)d_in[4];
  const float* b1 = (const float*)d_in[5];
  const float* W2 = (const float*)d_in[6];
  const float* b2 = (const float*)d_in[7];
  int n = in_sizes[0]/DF;
  int e = in_sizes[1]/2;
  const int* srcp = ei;
  const int* dstp = ei + e;

  char* ws = (char*)d_ws;
  size_t off=0;
  auto take=[&](size_t bytes)->char*{
    char* p = ws+off;
    off = (off+bytes+511)&~(size_t)511;
    return p;
  };
  int*   bcnt = (int*)  take((size_t)NB_MAX*4);
  int*   bbase= (int*)  take((size_t)(NB_MAX+1)*4);
  int*   bcur = (int*)  take((size_t)NB_MAX*4);
  int*   rp   = (int*)  take((size_t)(n+1)*4);
  int*   csr  = (int*)  take((size_t)e*4);
  float* dinv = (float*)take((size_t)n*4);
  float* bufA = (float*)take((size_t)n*DF*4);
  float* bufB = (float*)take((size_t)n*DF*4);
  int2*  binned = (int2*)bufB;   // dead before first write of bufB

  hipMemsetAsync(bcnt, 0, (size_t)NB_MAX*4, stream);

  int nb   = (n + RB-1) >> RB_SHIFT;
  int ncb  = (e + CHUNK-1) / CHUNK;
  k_bhist     <<<ncb, 256, 0, stream>>>(dstp, bcnt, e);
  k_bscan     <<<1,   256, 0, stream>>>(bcnt, bbase, bcur, e);
  k_binscatter<<<ncb, 256, 0, stream>>>(srcp, dstp, bcur, binned, e);
  k_localcsr  <<<nb,  256, 0, stream>>>(binned, bbase, rp, csr, dinv, n, e);

  int nfb = (n+31)/32;
  k_prescale<<<(n*(DF/4)+255)/256, 256, 0, stream>>>(x, dinv, bufA, n);
  // layer 1: gather g0(bufA) -> bufB = dinv*relu(y)
  k_fused   <<<nfb, 256, 0, stream>>>(bufA, rp, csr, dinv, W0, b0, bufB, n, 1);
  // layer 2: gather g1(bufB) -> bufA = relu(y)  (plain h2)
  k_fused   <<<nfb, 256, 0, stream>>>(bufB, rp, csr, dinv, W1, b1, bufA, n, 0);
  // layer 3: ht = dinv*(h2 @ W2) in bufB, then aggregate
  k_gemm5   <<<(n+31)/32, 256, 0, stream>>>(bufA, W2, dinv, (float*)bufB, n);
  k_agg5    <<<((n*8)+255)/256, 256, 0, stream>>>((float*)bufB, rp, csr, dinv, b2, (float*)d_out, n);
}